// Round 1
// baseline (12930.540 us; speedup 1.0000x reference)
//
#include <hip/hip_runtime.h>

// ---------------------------------------------------------------------------
// Decomposable attention model, fp32 correctness-first implementation.
// Softmax computed WITHOUT max subtraction (exp args ~2-4, fp32-safe by >30
// orders of magnitude) which lets numerator+denominator accumulate in one
// fused pass: out_i = (sum_j exp(Fa_i.Fb_j) * S_j) / (sum_j exp(Fa_i.Fb_j)).
// ---------------------------------------------------------------------------

// Y[M,N] = relu( [X1|X2] @ W^T + b ),  W is [N,K], K = K1+K2.
// 64x64 tile, 256 threads, 4x4 microtile, BK=16.
__global__ __launch_bounds__(256) void linear_relu_kernel(
    const float* __restrict__ X1, int K1,
    const float* __restrict__ X2, int K2,
    const float* __restrict__ W, const float* __restrict__ bias,
    float* __restrict__ Y, int M, int N)
{
    const int K = K1 + K2;
    __shared__ float Xs[16][68];   // [kk][row]
    __shared__ float Ws[16][68];   // [kk][col]
    const int bm = blockIdx.x * 64;
    const int bn = blockIdx.y * 64;
    const int tid = threadIdx.x;
    const int tx = tid & 15, ty = tid >> 4;
    const int lrow = tid >> 2;         // 0..63
    const int lk0  = (tid & 3) * 4;    // 0,4,8,12

    float acc[4][4] = {{0.f, 0.f, 0.f, 0.f}};

    for (int k0 = 0; k0 < K; k0 += 16) {
#pragma unroll
        for (int m = 0; m < 4; ++m) {
            int kk = lk0 + m;
            int k = k0 + kk;
            float v = 0.f;
            int row = bm + lrow;
            if (k < K1)      v = X1[(size_t)row * K1 + k];
            else if (k < K)  v = X2[(size_t)row * K2 + (k - K1)];
            Xs[kk][lrow] = v;
        }
#pragma unroll
        for (int m = 0; m < 4; ++m) {
            int kk = lk0 + m;
            int k = k0 + kk;
            int n = bn + lrow;
            float v = 0.f;
            if (n < N && k < K) v = W[(size_t)n * K + k];
            Ws[kk][lrow] = v;
        }
        __syncthreads();
#pragma unroll
        for (int kk = 0; kk < 16; ++kk) {
            float4 a4 = *(const float4*)&Xs[kk][ty * 4];
            float4 b4 = *(const float4*)&Ws[kk][tx * 4];
            float av[4] = {a4.x, a4.y, a4.z, a4.w};
            float bv[4] = {b4.x, b4.y, b4.z, b4.w};
#pragma unroll
            for (int i = 0; i < 4; ++i)
#pragma unroll
                for (int j = 0; j < 4; ++j)
                    acc[i][j] = fmaf(av[i], bv[j], acc[i][j]);
        }
        __syncthreads();
    }

#pragma unroll
    for (int i = 0; i < 4; ++i) {
        int row = bm + ty * 4 + i;
#pragma unroll
        for (int j = 0; j < 4; ++j) {
            int col = bn + tx * 4 + j;
            if (col < N) {
                float v = acc[i][j] + bias[col];
                Y[(size_t)row * N + col] = fmaxf(v, 0.f);
            }
        }
    }
}

// O[i,:] = (sum_j exp(A_i . B_j) * S[j,:]) / (sum_j exp(A_i . B_j))
// A: [LA][200], B: [LB][200], S: [LB][300], O: [LA][300]
// Block: 256 threads handles 32 rows of A; loops j in chunks of 64.
__global__ __launch_bounds__(256) void attend_kernel(
    const float* __restrict__ A,
    const float* __restrict__ B,
    const float* __restrict__ S,
    float* __restrict__ O,
    int LA, int LB)
{
    __shared__ float As[8][34];    // [kk][row 0..31]
    __shared__ float Bs[8][68];    // [kk][col 0..63]
    __shared__ float Wt[32][65];   // exp(E) tile [row][j]

    const int ib = blockIdx.x * 32;
    const int tid = threadIdx.x;
    const int tx = tid & 15, ty = tid >> 4;   // phase-1: rows ty*2.., cols tx*4..
    const int pr = tid >> 3, pc = tid & 7;    // phase-2: row pr, col lane pc
    const int srow = tid >> 3;                // 0..31 (staging)
    const int skk  = tid & 7;

    float acc[10][4];
#pragma unroll
    for (int k = 0; k < 10; ++k)
#pragma unroll
        for (int j = 0; j < 4; ++j) acc[k][j] = 0.f;
    float denom = 0.f;

    for (int jb = 0; jb < LB; jb += 64) {
        // ---- phase 1: E tile [32 x 64], K = 200 ----
        float e[2][4] = {{0.f, 0.f, 0.f, 0.f}};
        for (int k0 = 0; k0 < 200; k0 += 8) {
            As[skk][srow]      = A[(size_t)(ib + srow) * 200 + k0 + skk];
            Bs[skk][srow]      = B[(size_t)(jb + srow) * 200 + k0 + skk];
            Bs[skk][32 + srow] = B[(size_t)(jb + 32 + srow) * 200 + k0 + skk];
            __syncthreads();
#pragma unroll
            for (int kk = 0; kk < 8; ++kk) {
                float2 a2 = *(const float2*)&As[kk][ty * 2];
                float4 b4 = *(const float4*)&Bs[kk][tx * 4];
                e[0][0] = fmaf(a2.x, b4.x, e[0][0]);
                e[0][1] = fmaf(a2.x, b4.y, e[0][1]);
                e[0][2] = fmaf(a2.x, b4.z, e[0][2]);
                e[0][3] = fmaf(a2.x, b4.w, e[0][3]);
                e[1][0] = fmaf(a2.y, b4.x, e[1][0]);
                e[1][1] = fmaf(a2.y, b4.y, e[1][1]);
                e[1][2] = fmaf(a2.y, b4.z, e[1][2]);
                e[1][3] = fmaf(a2.y, b4.w, e[1][3]);
            }
            __syncthreads();
        }
        // exp -> Wt
#pragma unroll
        for (int i = 0; i < 2; ++i)
#pragma unroll
            for (int j = 0; j < 4; ++j)
                Wt[ty * 2 + i][tx * 4 + j] = __expf(e[i][j]);
        __syncthreads();

        // ---- phase 2: acc += Wt @ S_chunk ; denom += rowsum(Wt) ----
        const float* Sbase = S + (size_t)jb * 300;
        for (int j = 0; j < 64; ++j) {
            float p = Wt[pr][j];
            denom += p;
            const float* Srow = Sbase + (size_t)j * 300;
#pragma unroll
            for (int k = 0; k < 10; ++k) {
                int col = pc * 4 + 32 * k;
                if (col < 300) {
                    float4 s4 = *(const float4*)&Srow[col];
                    acc[k][0] = fmaf(p, s4.x, acc[k][0]);
                    acc[k][1] = fmaf(p, s4.y, acc[k][1]);
                    acc[k][2] = fmaf(p, s4.z, acc[k][2]);
                    acc[k][3] = fmaf(p, s4.w, acc[k][3]);
                }
            }
        }
        __syncthreads();
    }

    const float inv = 1.f / denom;
    float* Orow = O + (size_t)(ib + pr) * 300;
#pragma unroll
    for (int k = 0; k < 10; ++k) {
        int col = pc * 4 + 32 * k;
        if (col < 300) {
            float4 v;
            v.x = acc[k][0] * inv;
            v.y = acc[k][1] * inv;
            v.z = acc[k][2] * inv;
            v.w = acc[k][3] * inv;
            *(float4*)&Orow[col] = v;
        }
    }
}

// out[c] = sum_r V[r][c]   (one block per column)
__global__ __launch_bounds__(256) void colsum_kernel(
    const float* __restrict__ V, float* __restrict__ out, int rows, int cols)
{
    const int c = blockIdx.x;
    float s = 0.f;
    for (int r = threadIdx.x; r < rows; r += 256)
        s += V[(size_t)r * cols + c];
    __shared__ float red[256];
    red[threadIdx.x] = s;
    __syncthreads();
    for (int off = 128; off > 0; off >>= 1) {
        if (threadIdx.x < off) red[threadIdx.x] += red[threadIdx.x + off];
        __syncthreads();
    }
    if (threadIdx.x == 0) out[c] = red[0];
}

// logits = relu(hx @ Hw1^T + Hb1) @ Hw2^T + Hb2 ; out = softmax(logits)
__global__ __launch_bounds__(256) void head_kernel(
    const float* __restrict__ hsum,
    const float* __restrict__ Hw1, const float* __restrict__ Hb1,
    const float* __restrict__ Hw2, const float* __restrict__ Hb2,
    float* __restrict__ out)
{
    __shared__ float hx[400];
    __shared__ float hr[200];
    __shared__ float lg[3];
    const int t = threadIdx.x;
    for (int i = t; i < 400; i += 256) hx[i] = hsum[i];
    __syncthreads();
    if (t < 200) {
        float a = Hb1[t];
        for (int k = 0; k < 400; ++k) a = fmaf(hx[k], Hw1[t * 400 + k], a);
        hr[t] = fmaxf(a, 0.f);
    }
    __syncthreads();
    if (t < 3) {
        float a = Hb2[t];
        for (int k = 0; k < 200; ++k) a = fmaf(hr[k], Hw2[t * 200 + k], a);
        lg[t] = a;
    }
    __syncthreads();
    if (t == 0) {
        float m = fmaxf(lg[0], fmaxf(lg[1], lg[2]));
        float e0 = __expf(lg[0] - m);
        float e1 = __expf(lg[1] - m);
        float e2 = __expf(lg[2] - m);
        float s = e0 + e1 + e2;
        out[0] = e0 / s;
        out[1] = e1 / s;
        out[2] = e2 / s;
    }
}

extern "C" void kernel_launch(void* const* d_in, const int* in_sizes, int n_in,
                              void* d_out, int out_size, void* d_ws, size_t ws_size,
                              hipStream_t stream)
{
    const float* sen1 = (const float*)d_in[0];
    const float* sen2 = (const float*)d_in[1];
    const float* F_w1 = (const float*)d_in[2];
    const float* F_b1 = (const float*)d_in[3];
    const float* F_w2 = (const float*)d_in[4];
    const float* F_b2 = (const float*)d_in[5];
    const float* G_w1 = (const float*)d_in[6];
    const float* G_b1 = (const float*)d_in[7];
    const float* G_w2 = (const float*)d_in[8];
    const float* G_b2 = (const float*)d_in[9];
    const float* H_w1 = (const float*)d_in[10];
    const float* H_b1 = (const float*)d_in[11];
    const float* H_w2 = (const float*)d_in[12];
    const float* H_b2 = (const float*)d_in[13];
    float* out = (float*)d_out;

    const int L = 8192;
    float* ws    = (float*)d_ws;
    float* Fa    = ws;                    // 8192*200
    float* Fb    = Fa   + L * 200;        // 8192*200
    float* h     = Fb   + L * 200;        // 8192*200 (temp, reused)
    float* beta  = h    + L * 200;        // 8192*300
    float* alpha = beta + L * 300;        // 8192*300
    float* v1    = alpha + L * 300;       // 8192*200
    float* v2    = v1   + L * 200;        // 8192*200
    float* hsum  = v2   + L * 200;        // 400

    dim3 blk(256);
    dim3 gLin(L / 64, 4);   // N=200 -> 4 col blocks

    // F MLP on sen1 -> Fa
    hipLaunchKernelGGL(linear_relu_kernel, gLin, blk, 0, stream,
                       sen1, 300, (const float*)nullptr, 0, F_w1, F_b1, h, L, 200);
    hipLaunchKernelGGL(linear_relu_kernel, gLin, blk, 0, stream,
                       h, 200, (const float*)nullptr, 0, F_w2, F_b2, Fa, L, 200);
    // F MLP on sen2 -> Fb
    hipLaunchKernelGGL(linear_relu_kernel, gLin, blk, 0, stream,
                       sen2, 300, (const float*)nullptr, 0, F_w1, F_b1, h, L, 200);
    hipLaunchKernelGGL(linear_relu_kernel, gLin, blk, 0, stream,
                       h, 200, (const float*)nullptr, 0, F_w2, F_b2, Fb, L, 200);

    // beta  = softmax_rows(E) @ sen2 ;  alpha = softmax_cols(E)^T @ sen1
    hipLaunchKernelGGL(attend_kernel, dim3(L / 32), blk, 0, stream,
                       Fa, Fb, sen2, beta, L, L);
    hipLaunchKernelGGL(attend_kernel, dim3(L / 32), blk, 0, stream,
                       Fb, Fa, sen1, alpha, L, L);

    // G MLP: v1 = G(concat(sen1, beta)), v2 = G(concat(sen2, alpha))
    hipLaunchKernelGGL(linear_relu_kernel, gLin, blk, 0, stream,
                       sen1, 300, beta, 300, G_w1, G_b1, h, L, 200);
    hipLaunchKernelGGL(linear_relu_kernel, gLin, blk, 0, stream,
                       h, 200, (const float*)nullptr, 0, G_w2, G_b2, v1, L, 200);
    hipLaunchKernelGGL(linear_relu_kernel, gLin, blk, 0, stream,
                       sen2, 300, alpha, 300, G_w1, G_b1, h, L, 200);
    hipLaunchKernelGGL(linear_relu_kernel, gLin, blk, 0, stream,
                       h, 200, (const float*)nullptr, 0, G_w2, G_b2, v2, L, 200);

    // column sums -> hsum[400]
    hipLaunchKernelGGL(colsum_kernel, dim3(200), blk, 0, stream, v1, hsum, L, 200);
    hipLaunchKernelGGL(colsum_kernel, dim3(200), blk, 0, stream, v2, hsum + 200, L, 200);

    // head -> out[3]
    hipLaunchKernelGGL(head_kernel, dim3(1), blk, 0, stream,
                       hsum, H_w1, H_b1, H_w2, H_b2, out);
}

// Round 2
// 1169.722 us; speedup vs baseline: 11.0544x; 11.0544x over previous
//
#include <hip/hip_runtime.h>
#include <hip/hip_bf16.h>

// ---------------------------------------------------------------------------
// Decomposable attention. bf16 MFMA for the O(L^2) attend; fp32 MLPs.
// Softmax without max subtraction (E ~ 2..5, fp32 exp is safe), so
// numerator+denominator accumulate in one fused flash pass.
// ---------------------------------------------------------------------------

typedef __attribute__((ext_vector_type(8))) short short8;   // 8 bf16
typedef __attribute__((ext_vector_type(4))) float f32x4;

__device__ inline ushort f2bf(float f) {
    union { float f; unsigned u; } v{f};
    unsigned r = v.u + 0x7FFF + ((v.u >> 16) & 1);
    return (ushort)(r >> 16);
}

// Y[M,N] = relu( [X1|X2] @ W^T + b ). If Ybf != null, write bf16 to
// Ybf[row*224+col] (cols >= N zero-padded to 224) instead of f32 Y.
__global__ __launch_bounds__(256) void linear_relu_kernel(
    const float* __restrict__ X1, int K1,
    const float* __restrict__ X2, int K2,
    const float* __restrict__ W, const float* __restrict__ bias,
    float* __restrict__ Y, ushort* __restrict__ Ybf, int M, int N)
{
    const int K = K1 + K2;
    __shared__ float Xs[16][68];
    __shared__ float Ws[16][68];
    const int bm = blockIdx.x * 64;
    const int bn = blockIdx.y * 64;
    const int tid = threadIdx.x;
    const int tx = tid & 15, ty = tid >> 4;
    const int lrow = tid >> 2;
    const int lk0  = (tid & 3) * 4;

    float acc[4][4] = {{0.f, 0.f, 0.f, 0.f}};

    for (int k0 = 0; k0 < K; k0 += 16) {
#pragma unroll
        for (int m = 0; m < 4; ++m) {
            int kk = lk0 + m;
            int k = k0 + kk;
            float v = 0.f;
            int row = bm + lrow;
            if (k < K1)      v = X1[(size_t)row * K1 + k];
            else if (k < K)  v = X2[(size_t)row * K2 + (k - K1)];
            Xs[kk][lrow] = v;
        }
#pragma unroll
        for (int m = 0; m < 4; ++m) {
            int kk = lk0 + m;
            int k = k0 + kk;
            int n = bn + lrow;
            float v = 0.f;
            if (n < N && k < K) v = W[(size_t)n * K + k];
            Ws[kk][lrow] = v;
        }
        __syncthreads();
#pragma unroll
        for (int kk = 0; kk < 16; ++kk) {
            float4 a4 = *(const float4*)&Xs[kk][ty * 4];
            float4 b4 = *(const float4*)&Ws[kk][tx * 4];
            float av[4] = {a4.x, a4.y, a4.z, a4.w};
            float bv[4] = {b4.x, b4.y, b4.z, b4.w};
#pragma unroll
            for (int i = 0; i < 4; ++i)
#pragma unroll
                for (int j = 0; j < 4; ++j)
                    acc[i][j] = fmaf(av[i], bv[j], acc[i][j]);
        }
        __syncthreads();
    }

#pragma unroll
    for (int i = 0; i < 4; ++i) {
        int row = bm + ty * 4 + i;
#pragma unroll
        for (int j = 0; j < 4; ++j) {
            int col = bn + tx * 4 + j;
            if (Ybf) {
                if (col < 224) {
                    float v = (col < N) ? fmaxf(acc[i][j] + bias[col], 0.f) : 0.f;
                    Ybf[(size_t)row * 224 + col] = f2bf(v);
                }
            } else if (col < N) {
                float v = acc[i][j] + bias[col];
                Y[(size_t)row * N + col] = fmaxf(v, 0.f);
            }
        }
    }
}

// X [rows=8192][cols=300] f32 -> Xt [colsPad=320][8192] bf16 (pad rows zero)
__global__ __launch_bounds__(256) void transpose_bf16_kernel(
    const float* __restrict__ X, ushort* __restrict__ Xt, int rows, int cols, int colsPad)
{
    __shared__ float t[64][65];
    const int r0 = blockIdx.x * 64, c0 = blockIdx.y * 64;
    const int tc = threadIdx.x & 63, tr = threadIdx.x >> 6;
    for (int rr = tr; rr < 64; rr += 4) {
        int c = c0 + tc;
        t[rr][tc] = (c < cols) ? X[(size_t)(r0 + rr) * cols + c] : 0.f;
    }
    __syncthreads();
    for (int rr = tr; rr < 64; rr += 4) {
        int oc = c0 + rr;
        if (oc < colsPad)
            Xt[(size_t)oc * rows + r0 + tc] = f2bf(t[tc][rr]);
    }
}

// Fused both-direction flash attend.
// dir0: O=betaA = softmax_rows(FaA.FbA^T) @ S  with St = sen2^T (bf16)
// dir1: same with (Fa,Fb) swapped and St = sen1^T.
// A,Fb: [8192][224] bf16 (K padded).  St: [320][8192] bf16 (d padded, j-major).
// Block: 256 thr = 4 waves, 32 Q-rows. wave = (strip = w&1 -> i-half,
// jhalf = w>>1 -> j-half in E phase / d-half in PV phase).
__global__ __launch_bounds__(256) void attend_mfma_kernel(
    const ushort* __restrict__ FaA, const ushort* __restrict__ FbA,
    const ushort* __restrict__ StA, float* __restrict__ OA,
    const ushort* __restrict__ FaB, const ushort* __restrict__ FbB,
    const ushort* __restrict__ StB, float* __restrict__ OB)
{
    const int b = blockIdx.x;
    const int dir = b & 1;
    const ushort* A  = dir ? FaB : FaA;
    const ushort* B  = dir ? FbB : FbA;
    const ushort* St = dir ? StB : StA;
    float* O = dir ? OB : OA;
    const int ib = (b >> 1) * 32;

    const int tid  = threadIdx.x;
    const int wave = tid >> 6;
    const int lane = tid & 63;
    const int strip = wave & 1;
    const int jhalf = wave >> 1;
    const int lg = lane >> 4;   // 0..3
    const int lr = lane & 15;   // 0..15

    __shared__ ushort Pl[32][72];          // exp(E) tile, bf16, +8 pad
    __shared__ float dled[2][2][16];       // [jhalf][strip][i16] denom partials

    f32x4 acc[10];
#pragma unroll
    for (int t = 0; t < 10; ++t) acc[t] = f32x4{0.f, 0.f, 0.f, 0.f};
    float dsum[4] = {0.f, 0.f, 0.f, 0.f};

    // Hoist A-fragments (constant over j): i = ib + strip*16 + lr, 7 k-steps
    const ushort* Arow = A + (size_t)(ib + strip * 16 + lr) * 224 + lg * 8;
    short8 afr[7];
#pragma unroll
    for (int k = 0; k < 7; ++k) afr[k] = *(const short8*)(Arow + k * 32);

    for (int jb = 0; jb < 8192; jb += 64) {
        // ---- E phase: wave computes E[16i x 32j] for its (strip, jhalf) ----
        f32x4 e0 = f32x4{0.f, 0.f, 0.f, 0.f};
        f32x4 e1 = f32x4{0.f, 0.f, 0.f, 0.f};
        const ushort* Brow0 = B + (size_t)(jb + jhalf * 32 + lr) * 224 + lg * 8;
        const ushort* Brow1 = Brow0 + (size_t)16 * 224;
#pragma unroll
        for (int k = 0; k < 7; ++k) {
            short8 bf0 = *(const short8*)(Brow0 + k * 32);
            short8 bf1 = *(const short8*)(Brow1 + k * 32);
            e0 = __builtin_amdgcn_mfma_f32_16x16x32_bf16(afr[k], bf0, e0, 0, 0, 0);
            e1 = __builtin_amdgcn_mfma_f32_16x16x32_bf16(afr[k], bf1, e1, 0, 0, 0);
        }
        // exp (no max sub), row-sum across 16 lanes, bf16 -> LDS
        float x0[4], x1[4], part[4];
#pragma unroll
        for (int r = 0; r < 4; ++r) {
            x0[r] = __expf(e0[r]);
            x1[r] = __expf(e1[r]);
            part[r] = x0[r] + x1[r];
        }
#pragma unroll
        for (int m = 1; m < 16; m <<= 1)
#pragma unroll
            for (int r = 0; r < 4; ++r) part[r] += __shfl_xor(part[r], m);
#pragma unroll
        for (int r = 0; r < 4; ++r) dsum[r] += part[r];
#pragma unroll
        for (int r = 0; r < 4; ++r) {
            int il = strip * 16 + lg * 4 + r;
            Pl[il][jhalf * 32 + lr]      = f2bf(x0[r]);
            Pl[il][jhalf * 32 + 16 + lr] = f2bf(x1[r]);
        }
        __syncthreads();

        // ---- PV phase: wave computes O[16i x 160d] for (strip, d-half=jhalf)
        const ushort* Sb = St + (size_t)(jhalf * 160) * 8192 + jb + lg * 8;
#pragma unroll
        for (int j0 = 0; j0 < 64; j0 += 32) {
            short8 pf = *(const short8*)&Pl[strip * 16 + lr][j0 + lg * 8];
#pragma unroll
            for (int t = 0; t < 10; ++t) {
                short8 sf = *(const short8*)(Sb + (size_t)(t * 16 + lr) * 8192 + j0);
                acc[t] = __builtin_amdgcn_mfma_f32_16x16x32_bf16(pf, sf, acc[t], 0, 0, 0);
            }
        }
        __syncthreads();
    }

    // combine denominators across j-half waves
    if (lr == 0) {
#pragma unroll
        for (int r = 0; r < 4; ++r) dled[jhalf][strip][lg * 4 + r] = dsum[r];
    }
    __syncthreads();
    float inv[4];
#pragma unroll
    for (int r = 0; r < 4; ++r)
        inv[r] = 1.f / (dled[0][strip][lg * 4 + r] + dled[1][strip][lg * 4 + r]);

    // write O: i = ib + strip*16 + lg*4 + r ; d = jhalf*160 + t*16 + lr
#pragma unroll
    for (int t = 0; t < 10; ++t) {
        int d = jhalf * 160 + t * 16 + lr;
        if (d < 300) {
#pragma unroll
            for (int r = 0; r < 4; ++r) {
                int i = ib + strip * 16 + lg * 4 + r;
                O[(size_t)i * 300 + d] = acc[t][r] * inv[r];
            }
        }
    }
}

// out[c] = sum_r V[r][c]   (one block per column)
__global__ __launch_bounds__(256) void colsum_kernel(
    const float* __restrict__ V, float* __restrict__ out, int rows, int cols)
{
    const int c = blockIdx.x;
    float s = 0.f;
    for (int r = threadIdx.x; r < rows; r += 256)
        s += V[(size_t)r * cols + c];
    __shared__ float red[256];
    red[threadIdx.x] = s;
    __syncthreads();
    for (int off = 128; off > 0; off >>= 1) {
        if (threadIdx.x < off) red[threadIdx.x] += red[threadIdx.x + off];
        __syncthreads();
    }
    if (threadIdx.x == 0) out[c] = red[0];
}

__global__ __launch_bounds__(256) void head_kernel(
    const float* __restrict__ hsum,
    const float* __restrict__ Hw1, const float* __restrict__ Hb1,
    const float* __restrict__ Hw2, const float* __restrict__ Hb2,
    float* __restrict__ out)
{
    __shared__ float hx[400];
    __shared__ float hr[200];
    __shared__ float lg[3];
    const int t = threadIdx.x;
    for (int i = t; i < 400; i += 256) hx[i] = hsum[i];
    __syncthreads();
    if (t < 200) {
        float a = Hb1[t];
        for (int k = 0; k < 400; ++k) a = fmaf(hx[k], Hw1[t * 400 + k], a);
        hr[t] = fmaxf(a, 0.f);
    }
    __syncthreads();
    if (t < 3) {
        float a = Hb2[t];
        for (int k = 0; k < 200; ++k) a = fmaf(hr[k], Hw2[t * 200 + k], a);
        lg[t] = a;
    }
    __syncthreads();
    if (t == 0) {
        float m = fmaxf(lg[0], fmaxf(lg[1], lg[2]));
        float e0 = __expf(lg[0] - m);
        float e1 = __expf(lg[1] - m);
        float e2 = __expf(lg[2] - m);
        float s = e0 + e1 + e2;
        out[0] = e0 / s;
        out[1] = e1 / s;
        out[2] = e2 / s;
    }
}

extern "C" void kernel_launch(void* const* d_in, const int* in_sizes, int n_in,
                              void* d_out, int out_size, void* d_ws, size_t ws_size,
                              hipStream_t stream)
{
    const float* sen1 = (const float*)d_in[0];
    const float* sen2 = (const float*)d_in[1];
    const float* F_w1 = (const float*)d_in[2];
    const float* F_b1 = (const float*)d_in[3];
    const float* F_w2 = (const float*)d_in[4];
    const float* F_b2 = (const float*)d_in[5];
    const float* G_w1 = (const float*)d_in[6];
    const float* G_b1 = (const float*)d_in[7];
    const float* G_w2 = (const float*)d_in[8];
    const float* G_b2 = (const float*)d_in[9];
    const float* H_w1 = (const float*)d_in[10];
    const float* H_b1 = (const float*)d_in[11];
    const float* H_w2 = (const float*)d_in[12];
    const float* H_b2 = (const float*)d_in[13];
    float* out = (float*)d_out;

    const int L = 8192;
    char* w = (char*)d_ws;
    ushort* Fa16 = (ushort*)w;  w += (size_t)L * 224 * 2;
    ushort* Fb16 = (ushort*)w;  w += (size_t)L * 224 * 2;
    ushort* St1  = (ushort*)w;  w += (size_t)320 * L * 2;
    ushort* St2  = (ushort*)w;  w += (size_t)320 * L * 2;
    float*  h    = (float*)w;   w += (size_t)L * 200 * 4;
    float*  beta = (float*)w;   w += (size_t)L * 300 * 4;
    float*  alpha= (float*)w;   w += (size_t)L * 300 * 4;
    float*  v1   = (float*)w;   w += (size_t)L * 200 * 4;
    float*  v2   = (float*)w;   w += (size_t)L * 200 * 4;
    float*  hsum = (float*)w;

    dim3 blk(256);
    dim3 gLin(L / 64, 4);

    // sen^T -> bf16 [320][8192]
    hipLaunchKernelGGL(transpose_bf16_kernel, dim3(L / 64, 5), blk, 0, stream,
                       sen1, St1, L, 300, 320);
    hipLaunchKernelGGL(transpose_bf16_kernel, dim3(L / 64, 5), blk, 0, stream,
                       sen2, St2, L, 300, 320);

    // F MLPs -> Fa16 / Fb16 (bf16, K-padded to 224)
    hipLaunchKernelGGL(linear_relu_kernel, gLin, blk, 0, stream,
                       sen1, 300, (const float*)nullptr, 0, F_w1, F_b1, h, (ushort*)nullptr, L, 200);
    hipLaunchKernelGGL(linear_relu_kernel, gLin, blk, 0, stream,
                       h, 200, (const float*)nullptr, 0, F_w2, F_b2, (float*)nullptr, Fa16, L, 200);
    hipLaunchKernelGGL(linear_relu_kernel, gLin, blk, 0, stream,
                       sen2, 300, (const float*)nullptr, 0, F_w1, F_b1, h, (ushort*)nullptr, L, 200);
    hipLaunchKernelGGL(linear_relu_kernel, gLin, blk, 0, stream,
                       h, 200, (const float*)nullptr, 0, F_w2, F_b2, (float*)nullptr, Fb16, L, 200);

    // fused flash attend, both directions
    hipLaunchKernelGGL(attend_mfma_kernel, dim3(2 * L / 32), blk, 0, stream,
                       Fa16, Fb16, St2, beta,
                       Fb16, Fa16, St1, alpha);

    // G MLPs
    hipLaunchKernelGGL(linear_relu_kernel, gLin, blk, 0, stream,
                       sen1, 300, beta, 300, G_w1, G_b1, h, (ushort*)nullptr, L, 200);
    hipLaunchKernelGGL(linear_relu_kernel, gLin, blk, 0, stream,
                       h, 200, (const float*)nullptr, 0, G_w2, G_b2, v1, (ushort*)nullptr, L, 200);
    hipLaunchKernelGGL(linear_relu_kernel, gLin, blk, 0, stream,
                       sen2, 300, alpha, 300, G_w1, G_b1, h, (ushort*)nullptr, L, 200);
    hipLaunchKernelGGL(linear_relu_kernel, gLin, blk, 0, stream,
                       h, 200, (const float*)nullptr, 0, G_w2, G_b2, v2, (ushort*)nullptr, L, 200);

    hipLaunchKernelGGL(colsum_kernel, dim3(200), blk, 0, stream, v1, hsum, L, 200);
    hipLaunchKernelGGL(colsum_kernel, dim3(200), blk, 0, stream, v2, hsum + 200, L, 200);

    hipLaunchKernelGGL(head_kernel, dim3(1), blk, 0, stream,
                       hsum, H_w1, H_b1, H_w2, H_b2, out);
}

// Round 3
// 899.427 us; speedup vs baseline: 14.3764x; 1.3005x over previous
//
#include <hip/hip_runtime.h>

typedef __attribute__((ext_vector_type(8))) short short8;   // 8 bf16
typedef __attribute__((ext_vector_type(4))) float f32x4;

__device__ inline ushort f2bf(float f) {
    union { float f; unsigned u; } v{f};
    unsigned r = v.u + 0x7FFF + ((v.u >> 16) & 1);
    return (ushort)(r >> 16);
}

// ---------------------------------------------------------------------------
// sen1/sen2 f32 [8192][300] -> Senb bf16 [16384][320] (zero-padded) and
// Xcat bf16 [16384][608]: cols 0..299 = sen, cols 600..607 = 0.
// (cols 300..599 are filled by the attend kernel.)
// ---------------------------------------------------------------------------
__global__ __launch_bounds__(256) void convert_inputs_kernel(
    const float* __restrict__ sen1, const float* __restrict__ sen2,
    ushort* __restrict__ Senb, ushort* __restrict__ Xcat)
{
    const int row = blockIdx.x * 8 + (threadIdx.x >> 5);
    const int c0 = threadIdx.x & 31;
    const float* src = (row < 8192) ? (sen1 + (size_t)row * 300)
                                    : (sen2 + (size_t)(row - 8192) * 300);
    ushort* sb = Senb + (size_t)row * 320;
    ushort* xc = Xcat + (size_t)row * 608;
    for (int c = c0; c < 320; c += 32) {
        ushort v = (c < 300) ? f2bf(src[c]) : (ushort)0;
        sb[c] = v;
        if (c < 300) xc[c] = v;
    }
    if (c0 < 8) xc[600 + c0] = 0;
}

// ---------------------------------------------------------------------------
// W [N][K] f32 -> Wb [224][KP] bf16 zero-padded; bias -> biasp [224] f32.
// One block per output row; 4 matrices in one launch (blockIdx / 224).
// ---------------------------------------------------------------------------
__global__ __launch_bounds__(256) void convert_weights_kernel(
    const float* __restrict__ W0, const float* __restrict__ b0,
    const float* __restrict__ W1, const float* __restrict__ b1,
    const float* __restrict__ W2, const float* __restrict__ b2,
    const float* __restrict__ W3, const float* __restrict__ b3,
    ushort* __restrict__ Wb0, float* __restrict__ bp0,
    ushort* __restrict__ Wb1, float* __restrict__ bp1,
    ushort* __restrict__ Wb2, float* __restrict__ bp2,
    ushort* __restrict__ Wb3, float* __restrict__ bp3)
{
    const int id = blockIdx.x;
    const int mat = id / 224, n = id % 224;
    const float* W; const float* b; ushort* Wb; float* bp; int N, K, KP;
    if (mat == 0)      { W = W0; b = b0; Wb = Wb0; bp = bp0; N = 200; K = 300; KP = 320; }
    else if (mat == 1) { W = W1; b = b1; Wb = Wb1; bp = bp1; N = 200; K = 200; KP = 224; }
    else if (mat == 2) { W = W2; b = b2; Wb = Wb2; bp = bp2; N = 200; K = 600; KP = 608; }
    else               { W = W3; b = b3; Wb = Wb3; bp = bp3; N = 200; K = 200; KP = 224; }
    for (int k = threadIdx.x; k < KP; k += 256)
        Wb[(size_t)n * KP + k] = (n < N && k < K) ? f2bf(W[(size_t)n * K + k]) : (ushort)0;
    if (threadIdx.x == 0) bp[n] = (n < N) ? b[n] : 0.f;
}

// ---------------------------------------------------------------------------
// sen f32 [8192][300] -> St bf16 [320][8192] transposed (pad rows zero).
// blockIdx.z picks sentence.
// ---------------------------------------------------------------------------
__global__ __launch_bounds__(256) void transpose_bf16_kernel(
    const float* __restrict__ s1, const float* __restrict__ s2,
    ushort* __restrict__ St1, ushort* __restrict__ St2)
{
    const float* X = blockIdx.z ? s2 : s1;
    ushort* Xt = blockIdx.z ? St2 : St1;
    __shared__ float t[64][65];
    const int r0 = blockIdx.x * 64, c0 = blockIdx.y * 64;
    const int tc = threadIdx.x & 63, tr = threadIdx.x >> 6;
    for (int rr = tr; rr < 64; rr += 4) {
        int c = c0 + tc;
        t[rr][tc] = (c < 300) ? X[(size_t)(r0 + rr) * 300 + c] : 0.f;
    }
    __syncthreads();
    for (int rr = tr; rr < 64; rr += 4) {
        int oc = c0 + rr;
        if (oc < 320)
            Xt[(size_t)oc * 8192 + r0 + tc] = f2bf(t[tc][rr]);
    }
}

// ---------------------------------------------------------------------------
// Y = relu(X @ Wb^T + biasp). X bf16 [M][KP], Wb bf16 [224][KP], biasp f32[224].
// One wave per block, 16 rows, 14 n-tiles (N padded to 224).
// If Ybf: write bf16 [M][224] (all cols; pad cols come out 0).
// Else:   write f32 [M][200] (cols < 200).
// ---------------------------------------------------------------------------
__global__ __launch_bounds__(64) void mfma_linear_kernel(
    const ushort* __restrict__ X, const ushort* __restrict__ Wb,
    const float* __restrict__ biasp, int KP,
    ushort* __restrict__ Ybf, float* __restrict__ Yf)
{
    const int r0 = blockIdx.x * 16;
    const int lane = threadIdx.x;
    const int lr = lane & 15, lg = lane >> 4;

    f32x4 acc[14];
#pragma unroll
    for (int t = 0; t < 14; ++t) acc[t] = f32x4{0.f, 0.f, 0.f, 0.f};

    const ushort* Xrow = X + (size_t)(r0 + lr) * KP + lg * 8;
    const ushort* Wrow = Wb + (size_t)lr * KP + lg * 8;

    for (int k0 = 0; k0 < KP; k0 += 32) {
        short8 a = *(const short8*)(Xrow + k0);
#pragma unroll
        for (int t = 0; t < 14; ++t) {
            short8 bfr = *(const short8*)(Wrow + (size_t)t * 16 * KP + k0);
            acc[t] = __builtin_amdgcn_mfma_f32_16x16x32_bf16(a, bfr, acc[t], 0, 0, 0);
        }
    }

    // C layout: col = lane&15 (n_local), row = (lane>>4)*4 + rr (i_local)
#pragma unroll
    for (int t = 0; t < 14; ++t) {
        int col = t * 16 + lr;
        float bv = biasp[col];
#pragma unroll
        for (int rr = 0; rr < 4; ++rr) {
            int row = r0 + lg * 4 + rr;
            float v = fmaxf(acc[t][rr] + bv, 0.f);
            if (Ybf) Ybf[(size_t)row * 224 + col] = f2bf(v);
            else if (col < 200) Yf[(size_t)row * 200 + col] = v;
        }
    }
}

// ---------------------------------------------------------------------------
// Fused both-direction flash attend. 16 Q-rows/block, 4 waves.
// dir0: rows i of beta = softmax_j(Fa_i . Fb_j) @ sen2 ; dir1 swapped.
// A,B: bf16 [8192][224]; St: bf16 [320][8192]; output bf16 -> Xcat col 300+.
// Wave w: E-quarter j in [jb+16w, jb+16w+16); PV d-quarter [80w, 80w+80).
// P tile double-buffered in LDS -> single barrier per iteration.
// ---------------------------------------------------------------------------
__global__ __launch_bounds__(256, 4) void attend_mfma_kernel(
    const ushort* __restrict__ FaFb, const ushort* __restrict__ St1,
    const ushort* __restrict__ St2, ushort* __restrict__ Xcat)
{
    const int b = blockIdx.x;
    const int dir = b & 1;
    const ushort* A  = FaFb + (dir ? (size_t)8192 * 224 : 0);
    const ushort* B  = FaFb + (dir ? 0 : (size_t)8192 * 224);
    const ushort* St = dir ? St1 : St2;
    const int ib = (b >> 1) * 16;

    const int tid = threadIdx.x;
    const int w = tid >> 6;
    const int lane = tid & 63;
    const int lr = lane & 15, lg = lane >> 4;

    __shared__ __align__(16) ushort Pl[2][16][72];
    __shared__ float dled[4][16];

    f32x4 acc[5];
#pragma unroll
    for (int t = 0; t < 5; ++t) acc[t] = f32x4{0.f, 0.f, 0.f, 0.f};
    float dsum[4] = {0.f, 0.f, 0.f, 0.f};

    // A fragments hoisted: row i = ib + lr, k-offset lg*8, 7 K-steps (K=224)
    const ushort* Arow = A + (size_t)(ib + lr) * 224 + lg * 8;
    short8 afr[7];
#pragma unroll
    for (int k = 0; k < 7; ++k) afr[k] = *(const short8*)(Arow + k * 32);

    const ushort* Bbase = B + (size_t)(w * 16 + lr) * 224 + lg * 8;
    const ushort* Sbase = St + (size_t)(w * 80 + lr) * 8192 + lg * 8;

    int buf = 0;
    for (int jb = 0; jb < 8192; jb += 64, buf ^= 1) {
        // ---- E: wave w computes E[16 x 16] at columns j = jb + 16w ----
        f32x4 e = f32x4{0.f, 0.f, 0.f, 0.f};
        const ushort* Brow = Bbase + (size_t)jb * 224;
#pragma unroll
        for (int k = 0; k < 7; ++k) {
            short8 bfr = *(const short8*)(Brow + k * 32);
            e = __builtin_amdgcn_mfma_f32_16x16x32_bf16(afr[k], bfr, e, 0, 0, 0);
        }
        // exp (no max-sub: args ~2..5), per-row partial sums, bf16 P -> LDS
        float x[4], part[4];
#pragma unroll
        for (int r = 0; r < 4; ++r) { x[r] = __expf(e[r]); part[r] = x[r]; }
#pragma unroll
        for (int m = 1; m < 16; m <<= 1)
#pragma unroll
            for (int r = 0; r < 4; ++r) part[r] += __shfl_xor(part[r], m);
#pragma unroll
        for (int r = 0; r < 4; ++r) dsum[r] += part[r];
        // C: col = lr (j_local), row = lg*4+r (i_local)
#pragma unroll
        for (int r = 0; r < 4; ++r)
            Pl[buf][lg * 4 + r][w * 16 + lr] = f2bf(x[r]);
        __syncthreads();

        // ---- PV: wave w handles d in [80w, 80w+80) over 64 j ----
#pragma unroll
        for (int j0 = 0; j0 < 64; j0 += 32) {
            short8 pf = *(const short8*)&Pl[buf][lr][j0 + lg * 8];
            const ushort* Srow = Sbase + jb + j0;
#pragma unroll
            for (int t = 0; t < 5; ++t) {
                short8 sf = *(const short8*)(Srow + (size_t)t * 16 * 8192);
                acc[t] = __builtin_amdgcn_mfma_f32_16x16x32_bf16(pf, sf, acc[t], 0, 0, 0);
            }
        }
        // no second barrier: next iteration writes the other P buffer
    }

    // combine denominators across the 4 j-quarter waves
    if (lr == 0) {
#pragma unroll
        for (int r = 0; r < 4; ++r) dled[w][lg * 4 + r] = dsum[r];
    }
    __syncthreads();
    float inv[4];
#pragma unroll
    for (int r = 0; r < 4; ++r)
        inv[r] = 1.f / (dled[0][lg * 4 + r] + dled[1][lg * 4 + r] +
                        dled[2][lg * 4 + r] + dled[3][lg * 4 + r]);

    // write normalized bf16 into Xcat cols 300..599
    // PV C: col = lr (d_local), row = lg*4+rr (i_local); d = 80w + 16t + lr
    ushort* Orow = Xcat + (size_t)(dir * 8192 + ib) * 608 + 300;
#pragma unroll
    for (int t = 0; t < 5; ++t) {
        int d = w * 80 + t * 16 + lr;
        if (d < 300) {
#pragma unroll
            for (int r = 0; r < 4; ++r)
                Orow[(size_t)(lg * 4 + r) * 608 + d] = f2bf(acc[t][r] * inv[r]);
        }
    }
}

// ---------------------------------------------------------------------------
// hsum[c] = sum_r v[r][c%200] over the half selected by c/200. c in [0,400).
// ---------------------------------------------------------------------------
__global__ __launch_bounds__(256) void colsum_kernel(
    const float* __restrict__ v, float* __restrict__ hsum)
{
    const int c = blockIdx.x;
    const float* V = v + (c < 200 ? 0 : (size_t)8192 * 200);
    const int col = c % 200;
    float s = 0.f;
    for (int r = threadIdx.x; r < 8192; r += 256)
        s += V[(size_t)r * 200 + col];
    __shared__ float red[256];
    red[threadIdx.x] = s;
    __syncthreads();
    for (int off = 128; off > 0; off >>= 1) {
        if (threadIdx.x < off) red[threadIdx.x] += red[threadIdx.x + off];
        __syncthreads();
    }
    if (threadIdx.x == 0) hsum[c] = red[0];
}

__global__ __launch_bounds__(256) void head_kernel(
    const float* __restrict__ hsum,
    const float* __restrict__ Hw1, const float* __restrict__ Hb1,
    const float* __restrict__ Hw2, const float* __restrict__ Hb2,
    float* __restrict__ out)
{
    __shared__ float hx[400];
    __shared__ float hr[200];
    __shared__ float lg[3];
    const int t = threadIdx.x;
    for (int i = t; i < 400; i += 256) hx[i] = hsum[i];
    __syncthreads();
    if (t < 200) {
        float a = Hb1[t];
        for (int k = 0; k < 400; ++k) a = fmaf(hx[k], Hw1[t * 400 + k], a);
        hr[t] = fmaxf(a, 0.f);
    }
    __syncthreads();
    if (t < 3) {
        float a = Hb2[t];
        for (int k = 0; k < 200; ++k) a = fmaf(hr[k], Hw2[t * 200 + k], a);
        lg[t] = a;
    }
    __syncthreads();
    if (t == 0) {
        float m = fmaxf(lg[0], fmaxf(lg[1], lg[2]));
        float e0 = __expf(lg[0] - m);
        float e1 = __expf(lg[1] - m);
        float e2 = __expf(lg[2] - m);
        float s = e0 + e1 + e2;
        out[0] = e0 / s;
        out[1] = e1 / s;
        out[2] = e2 / s;
    }
}

extern "C" void kernel_launch(void* const* d_in, const int* in_sizes, int n_in,
                              void* d_out, int out_size, void* d_ws, size_t ws_size,
                              hipStream_t stream)
{
    const float* sen1 = (const float*)d_in[0];
    const float* sen2 = (const float*)d_in[1];
    const float* F_w1 = (const float*)d_in[2];
    const float* F_b1 = (const float*)d_in[3];
    const float* F_w2 = (const float*)d_in[4];
    const float* F_b2 = (const float*)d_in[5];
    const float* G_w1 = (const float*)d_in[6];
    const float* G_b1 = (const float*)d_in[7];
    const float* G_w2 = (const float*)d_in[8];
    const float* G_b2 = (const float*)d_in[9];
    const float* H_w1 = (const float*)d_in[10];
    const float* H_b1 = (const float*)d_in[11];
    const float* H_w2 = (const float*)d_in[12];
    const float* H_b2 = (const float*)d_in[13];
    float* out = (float*)d_out;

    const int L = 8192;
    char* p = (char*)d_ws;
    ushort* Senb = (ushort*)p; p += (size_t)2 * L * 320 * 2;   // [16384][320]
    ushort* St1  = (ushort*)p; p += (size_t)320 * L * 2;       // [320][8192]
    ushort* St2  = (ushort*)p; p += (size_t)320 * L * 2;
    ushort* h16  = (ushort*)p; p += (size_t)2 * L * 224 * 2;   // [16384][224]
    ushort* FaFb = (ushort*)p; p += (size_t)2 * L * 224 * 2;   // [16384][224]
    ushort* Xcat = (ushort*)p; p += (size_t)2 * L * 608 * 2;   // [16384][608]
    float*  v    = (float*)p;  p += (size_t)2 * L * 200 * 4;   // [16384][200]
    ushort* WbF1 = (ushort*)p; p += (size_t)224 * 320 * 2;
    ushort* WbF2 = (ushort*)p; p += (size_t)224 * 224 * 2;
    ushort* WbG1 = (ushort*)p; p += (size_t)224 * 608 * 2;
    ushort* WbG2 = (ushort*)p; p += (size_t)224 * 224 * 2;
    float*  bpF1 = (float*)p;  p += 224 * 4;
    float*  bpF2 = (float*)p;  p += 224 * 4;
    float*  bpG1 = (float*)p;  p += 224 * 4;
    float*  bpG2 = (float*)p;  p += 224 * 4;
    float*  hsum = (float*)p;  p += 400 * 4;

    dim3 blk256(256);

    hipLaunchKernelGGL(convert_inputs_kernel, dim3(2 * L / 8), blk256, 0, stream,
                       sen1, sen2, Senb, Xcat);
    hipLaunchKernelGGL(transpose_bf16_kernel, dim3(L / 64, 5, 2), blk256, 0, stream,
                       sen1, sen2, St1, St2);
    hipLaunchKernelGGL(convert_weights_kernel, dim3(4 * 224), blk256, 0, stream,
                       F_w1, F_b1, F_w2, F_b2, G_w1, G_b1, G_w2, G_b2,
                       WbF1, bpF1, WbF2, bpF2, WbG1, bpG1, WbG2, bpG2);

    // F MLP (both sentences batched: M = 16384)
    hipLaunchKernelGGL(mfma_linear_kernel, dim3(2 * L / 16), dim3(64), 0, stream,
                       Senb, WbF1, bpF1, 320, h16, (float*)nullptr);
    hipLaunchKernelGGL(mfma_linear_kernel, dim3(2 * L / 16), dim3(64), 0, stream,
                       h16, WbF2, bpF2, 224, FaFb, (float*)nullptr);

    // fused flash attend (both directions), writes beta/alpha into Xcat
    hipLaunchKernelGGL(attend_mfma_kernel, dim3(2 * L / 16), blk256, 0, stream,
                       FaFb, St1, St2, Xcat);

    // G MLP (both sides batched)
    hipLaunchKernelGGL(mfma_linear_kernel, dim3(2 * L / 16), dim3(64), 0, stream,
                       Xcat, WbG1, bpG1, 608, h16, (float*)nullptr);
    hipLaunchKernelGGL(mfma_linear_kernel, dim3(2 * L / 16), dim3(64), 0, stream,
                       h16, WbG2, bpG2, 224, (ushort*)nullptr, v);

    hipLaunchKernelGGL(colsum_kernel, dim3(400), blk256, 0, stream, v, hsum);
    hipLaunchKernelGGL(head_kernel, dim3(1), blk256, 0, stream,
                       hsum, H_w1, H_b1, H_w2, H_b2, out);
}

// Round 4
// 356.244 us; speedup vs baseline: 36.2969x; 2.5248x over previous
//
#include <hip/hip_runtime.h>

typedef __attribute__((ext_vector_type(8))) short short8;   // 8 bf16
typedef __attribute__((ext_vector_type(4))) float f32x4;

__device__ inline ushort f2bf(float f) {
    union { float f; unsigned u; } v{f};
    unsigned r = v.u + 0x7FFF + ((v.u >> 16) & 1);
    return (ushort)(r >> 16);
}

// ---------------------------------------------------------------------------
// sen1/sen2 f32 [8192][300] -> Senb bf16 [16384][320] (zero-padded) and
// Xcat bf16 [16384][608]: cols 0..299 = sen, cols 600..607 = 0.
// (cols 300..599 are filled by the attend kernel.)
// ---------------------------------------------------------------------------
__global__ __launch_bounds__(256) void convert_inputs_kernel(
    const float* __restrict__ sen1, const float* __restrict__ sen2,
    ushort* __restrict__ Senb, ushort* __restrict__ Xcat)
{
    const int row = blockIdx.x * 8 + (threadIdx.x >> 5);
    const int c0 = threadIdx.x & 31;
    const float* src = (row < 8192) ? (sen1 + (size_t)row * 300)
                                    : (sen2 + (size_t)(row - 8192) * 300);
    ushort* sb = Senb + (size_t)row * 320;
    ushort* xc = Xcat + (size_t)row * 608;
    for (int c = c0; c < 320; c += 32) {
        ushort v = (c < 300) ? f2bf(src[c]) : (ushort)0;
        sb[c] = v;
        if (c < 300) xc[c] = v;
    }
    if (c0 < 8) xc[600 + c0] = 0;
}

// ---------------------------------------------------------------------------
// W [N][K] f32 -> Wb [224][KP] bf16 zero-padded; bias -> biasp [224] f32.
// ---------------------------------------------------------------------------
__global__ __launch_bounds__(256) void convert_weights_kernel(
    const float* __restrict__ W0, const float* __restrict__ b0,
    const float* __restrict__ W1, const float* __restrict__ b1,
    const float* __restrict__ W2, const float* __restrict__ b2,
    const float* __restrict__ W3, const float* __restrict__ b3,
    ushort* __restrict__ Wb0, float* __restrict__ bp0,
    ushort* __restrict__ Wb1, float* __restrict__ bp1,
    ushort* __restrict__ Wb2, float* __restrict__ bp2,
    ushort* __restrict__ Wb3, float* __restrict__ bp3)
{
    const int id = blockIdx.x;
    const int mat = id / 224, n = id % 224;
    const float* W; const float* b; ushort* Wb; float* bp; int N, K, KP;
    if (mat == 0)      { W = W0; b = b0; Wb = Wb0; bp = bp0; N = 200; K = 300; KP = 320; }
    else if (mat == 1) { W = W1; b = b1; Wb = Wb1; bp = bp1; N = 200; K = 200; KP = 224; }
    else if (mat == 2) { W = W2; b = b2; Wb = Wb2; bp = bp2; N = 200; K = 600; KP = 608; }
    else               { W = W3; b = b3; Wb = Wb3; bp = bp3; N = 200; K = 200; KP = 224; }
    for (int k = threadIdx.x; k < KP; k += 256)
        Wb[(size_t)n * KP + k] = (n < N && k < K) ? f2bf(W[(size_t)n * K + k]) : (ushort)0;
    if (threadIdx.x == 0) bp[n] = (n < N) ? b[n] : 0.f;
}

// ---------------------------------------------------------------------------
// sen f32 [8192][300] -> St bf16 [320][8192] transposed (pad rows zero).
// ---------------------------------------------------------------------------
__global__ __launch_bounds__(256) void transpose_bf16_kernel(
    const float* __restrict__ s1, const float* __restrict__ s2,
    ushort* __restrict__ St1, ushort* __restrict__ St2)
{
    const float* X = blockIdx.z ? s2 : s1;
    ushort* Xt = blockIdx.z ? St2 : St1;
    __shared__ float t[64][65];
    const int r0 = blockIdx.x * 64, c0 = blockIdx.y * 64;
    const int tc = threadIdx.x & 63, tr = threadIdx.x >> 6;
    for (int rr = tr; rr < 64; rr += 4) {
        int c = c0 + tc;
        t[rr][tc] = (c < 300) ? X[(size_t)(r0 + rr) * 300 + c] : 0.f;
    }
    __syncthreads();
    for (int rr = tr; rr < 64; rr += 4) {
        int oc = c0 + rr;
        if (oc < 320)
            Xt[(size_t)oc * 8192 + r0 + tc] = f2bf(t[tc][rr]);
    }
}

// ---------------------------------------------------------------------------
// Y = relu(X @ Wb^T + biasp). X bf16 [M][KP], Wb bf16 [224][KP], biasp f32[224].
// One wave per block, 16 rows, 14 n-tiles.
// ---------------------------------------------------------------------------
__global__ __launch_bounds__(64) void mfma_linear_kernel(
    const ushort* __restrict__ X, const ushort* __restrict__ Wb,
    const float* __restrict__ biasp, int KP,
    ushort* __restrict__ Ybf, float* __restrict__ Yf)
{
    const int r0 = blockIdx.x * 16;
    const int lane = threadIdx.x;
    const int lr = lane & 15, lg = lane >> 4;

    f32x4 acc[14];
#pragma unroll
    for (int t = 0; t < 14; ++t) acc[t] = f32x4{0.f, 0.f, 0.f, 0.f};

    const ushort* Xrow = X + (size_t)(r0 + lr) * KP + lg * 8;
    const ushort* Wrow = Wb + (size_t)lr * KP + lg * 8;

    for (int k0 = 0; k0 < KP; k0 += 32) {
        short8 a = *(const short8*)(Xrow + k0);
#pragma unroll
        for (int t = 0; t < 14; ++t) {
            short8 bfr = *(const short8*)(Wrow + (size_t)t * 16 * KP + k0);
            acc[t] = __builtin_amdgcn_mfma_f32_16x16x32_bf16(a, bfr, acc[t], 0, 0, 0);
        }
    }

#pragma unroll
    for (int t = 0; t < 14; ++t) {
        int col = t * 16 + lr;
        float bv = biasp[col];
#pragma unroll
        for (int rr = 0; rr < 4; ++rr) {
            int row = r0 + lg * 4 + rr;
            float v = fmaxf(acc[t][rr] + bv, 0.f);
            if (Ybf) Ybf[(size_t)row * 224 + col] = f2bf(v);
            else if (col < 200) Yf[(size_t)row * 200 + col] = v;
        }
    }
}

// ---------------------------------------------------------------------------
// Fused both-direction flash attend, 64 Q-rows per block, 4 waves, 1 block/CU.
// Wave w: E-phase owns j-quarter [jb+16w, jb+16w+16) x ALL 64 i (28 MFMA);
//         PV-phase owns d-quarter [80w, 80w+80) x ALL 64 i (40 MFMA).
// A-fragments (64 rows) hoisted to registers (112 VGPR). B prefetched one
// iter ahead; St loaded at iter top, consumed in PV after the barrier.
// P tile double-buffered in LDS -> single barrier per iteration.
// ---------------------------------------------------------------------------
__global__ __launch_bounds__(256, 1) void attend_mfma_kernel(
    const ushort* __restrict__ FaFb, const ushort* __restrict__ St1,
    const ushort* __restrict__ St2, ushort* __restrict__ Xcat)
{
    const int b = blockIdx.x;
    const int dir = b & 1;
    const ushort* A  = FaFb + (dir ? (size_t)8192 * 224 : 0);
    const ushort* B  = FaFb + (dir ? 0 : (size_t)8192 * 224);
    const ushort* St = dir ? St1 : St2;
    const int ib = (b >> 1) * 64;

    const int tid = threadIdx.x;
    const int w = tid >> 6;
    const int lane = tid & 63;
    const int lr = lane & 15, lg = lane >> 4;

    __shared__ __align__(16) ushort Pl[2][64][72];
    __shared__ float dled[4][64];

    f32x4 acc[4][5];   // [i-sub][d-tile]
#pragma unroll
    for (int s = 0; s < 4; ++s)
#pragma unroll
        for (int t = 0; t < 5; ++t) acc[s][t] = f32x4{0.f, 0.f, 0.f, 0.f};
    float dsum[4][4] = {{0.f}};

    // A fragments: rows i = ib + s*16 + lr, k-offset lg*8 + 32k (K=224)
    short8 afr[4][7];
#pragma unroll
    for (int s = 0; s < 4; ++s) {
        const ushort* Ar = A + (size_t)(ib + s * 16 + lr) * 224 + lg * 8;
#pragma unroll
        for (int k = 0; k < 7; ++k) afr[s][k] = *(const short8*)(Ar + k * 32);
    }

    // B current fragments: j-row = jb + w*16 + lr
    const ushort* Brow = B + (size_t)(w * 16 + lr) * 224 + lg * 8;
    short8 bfr[7];
#pragma unroll
    for (int k = 0; k < 7; ++k) bfr[k] = *(const short8*)(Brow + k * 32);

    const ushort* Sbase = St + (size_t)(w * 80 + lr) * 8192 + lg * 8;

    int buf = 0;
    for (int jb = 0; jb < 8192; jb += 64, buf ^= 1) {
        // St fragments for this jb: [d-tile][j-half]  (used in PV, loads early)
        short8 st[5][2];
#pragma unroll
        for (int t = 0; t < 5; ++t)
#pragma unroll
            for (int h = 0; h < 2; ++h)
                st[t][h] = *(const short8*)(Sbase + (size_t)t * 16 * 8192 + jb + h * 32);

        // ---- E: wave w computes E[64 i x 16 j] ----
        f32x4 e[4];
#pragma unroll
        for (int s = 0; s < 4; ++s) e[s] = f32x4{0.f, 0.f, 0.f, 0.f};
#pragma unroll
        for (int k = 0; k < 7; ++k)
#pragma unroll
            for (int s = 0; s < 4; ++s)
                e[s] = __builtin_amdgcn_mfma_f32_16x16x32_bf16(afr[s][k], bfr[k], e[s], 0, 0, 0);

        // exp (no max-sub: args ~2..5); per-lane partial denom; bf16 P -> LDS
#pragma unroll
        for (int s = 0; s < 4; ++s)
#pragma unroll
            for (int r = 0; r < 4; ++r) {
                float x = __expf(e[s][r]);
                dsum[s][r] += x;
                Pl[buf][s * 16 + lg * 4 + r][w * 16 + lr] = f2bf(x);
            }
        __syncthreads();

        // prefetch next B tile rows (used next iteration)
        if (jb + 64 < 8192) {
            const ushort* Bn = Brow + (size_t)(jb + 64) * 224;
#pragma unroll
            for (int k = 0; k < 7; ++k) bfr[k] = *(const short8*)(Bn + k * 32);
        }

        // ---- PV: wave w computes O[64 i x 80 d] over these 64 j ----
#pragma unroll
        for (int h = 0; h < 2; ++h) {
            short8 pf[4];
#pragma unroll
            for (int s = 0; s < 4; ++s)
                pf[s] = *(const short8*)&Pl[buf][s * 16 + lr][h * 32 + lg * 8];
#pragma unroll
            for (int s = 0; s < 4; ++s)
#pragma unroll
                for (int t = 0; t < 5; ++t)
                    acc[s][t] = __builtin_amdgcn_mfma_f32_16x16x32_bf16(pf[s], st[t][h], acc[s][t], 0, 0, 0);
        }
        // no second barrier: next iteration writes the other P buffer
    }

    // denominator: reduce over 16 lanes (j within quarter), then across waves
#pragma unroll
    for (int m = 1; m < 16; m <<= 1)
#pragma unroll
        for (int s = 0; s < 4; ++s)
#pragma unroll
            for (int r = 0; r < 4; ++r)
                dsum[s][r] += __shfl_xor(dsum[s][r], m);
    if (lr == 0) {
#pragma unroll
        for (int s = 0; s < 4; ++s)
#pragma unroll
            for (int r = 0; r < 4; ++r)
                dled[w][s * 16 + lg * 4 + r] = dsum[s][r];
    }
    __syncthreads();
    float inv[4][4];
#pragma unroll
    for (int s = 0; s < 4; ++s)
#pragma unroll
        for (int r = 0; r < 4; ++r) {
            int i = s * 16 + lg * 4 + r;
            inv[s][r] = 1.f / (dled[0][i] + dled[1][i] + dled[2][i] + dled[3][i]);
        }

    // write normalized bf16 into Xcat cols 300..599
    ushort* Obase = Xcat + (size_t)(dir * 8192 + ib) * 608 + 300;
#pragma unroll
    for (int t = 0; t < 5; ++t) {
        int d = w * 80 + t * 16 + lr;
        if (d < 300) {
#pragma unroll
            for (int s = 0; s < 4; ++s)
#pragma unroll
                for (int r = 0; r < 4; ++r)
                    Obase[(size_t)(s * 16 + lg * 4 + r) * 608 + d] = f2bf(acc[s][t][r] * inv[s][r]);
        }
    }
}

// ---------------------------------------------------------------------------
// hsum[c] = sum_r v[r][c%200] over the half selected by c/200. c in [0,400).
// ---------------------------------------------------------------------------
__global__ __launch_bounds__(256) void colsum_kernel(
    const float* __restrict__ v, float* __restrict__ hsum)
{
    const int c = blockIdx.x;
    const float* V = v + (c < 200 ? 0 : (size_t)8192 * 200);
    const int col = c % 200;
    float s = 0.f;
    for (int r = threadIdx.x; r < 8192; r += 256)
        s += V[(size_t)r * 200 + col];
    __shared__ float red[256];
    red[threadIdx.x] = s;
    __syncthreads();
    for (int off = 128; off > 0; off >>= 1) {
        if (threadIdx.x < off) red[threadIdx.x] += red[threadIdx.x + off];
        __syncthreads();
    }
    if (threadIdx.x == 0) hsum[c] = red[0];
}

__global__ __launch_bounds__(256) void head_kernel(
    const float* __restrict__ hsum,
    const float* __restrict__ Hw1, const float* __restrict__ Hb1,
    const float* __restrict__ Hw2, const float* __restrict__ Hb2,
    float* __restrict__ out)
{
    __shared__ float hx[400];
    __shared__ float hr[200];
    __shared__ float lg[3];
    const int t = threadIdx.x;
    for (int i = t; i < 400; i += 256) hx[i] = hsum[i];
    __syncthreads();
    if (t < 200) {
        float a = Hb1[t];
        for (int k = 0; k < 400; ++k) a = fmaf(hx[k], Hw1[t * 400 + k], a);
        hr[t] = fmaxf(a, 0.f);
    }
    __syncthreads();
    if (t < 3) {
        float a = Hb2[t];
        for (int k = 0; k < 200; ++k) a = fmaf(hr[k], Hw2[t * 200 + k], a);
        lg[t] = a;
    }
    __syncthreads();
    if (t == 0) {
        float m = fmaxf(lg[0], fmaxf(lg[1], lg[2]));
        float e0 = __expf(lg[0] - m);
        float e1 = __expf(lg[1] - m);
        float e2 = __expf(lg[2] - m);
        float s = e0 + e1 + e2;
        out[0] = e0 / s;
        out[1] = e1 / s;
        out[2] = e2 / s;
    }
}

extern "C" void kernel_launch(void* const* d_in, const int* in_sizes, int n_in,
                              void* d_out, int out_size, void* d_ws, size_t ws_size,
                              hipStream_t stream)
{
    const float* sen1 = (const float*)d_in[0];
    const float* sen2 = (const float*)d_in[1];
    const float* F_w1 = (const float*)d_in[2];
    const float* F_b1 = (const float*)d_in[3];
    const float* F_w2 = (const float*)d_in[4];
    const float* F_b2 = (const float*)d_in[5];
    const float* G_w1 = (const float*)d_in[6];
    const float* G_b1 = (const float*)d_in[7];
    const float* G_w2 = (const float*)d_in[8];
    const float* G_b2 = (const float*)d_in[9];
    const float* H_w1 = (const float*)d_in[10];
    const float* H_b1 = (const float*)d_in[11];
    const float* H_w2 = (const float*)d_in[12];
    const float* H_b2 = (const float*)d_in[13];
    float* out = (float*)d_out;

    const int L = 8192;
    char* p = (char*)d_ws;
    ushort* Senb = (ushort*)p; p += (size_t)2 * L * 320 * 2;   // [16384][320]
    ushort* St1  = (ushort*)p; p += (size_t)320 * L * 2;       // [320][8192]
    ushort* St2  = (ushort*)p; p += (size_t)320 * L * 2;
    ushort* h16  = (ushort*)p; p += (size_t)2 * L * 224 * 2;   // [16384][224]
    ushort* FaFb = (ushort*)p; p += (size_t)2 * L * 224 * 2;   // [16384][224]
    ushort* Xcat = (ushort*)p; p += (size_t)2 * L * 608 * 2;   // [16384][608]
    float*  v    = (float*)p;  p += (size_t)2 * L * 200 * 4;   // [16384][200]
    ushort* WbF1 = (ushort*)p; p += (size_t)224 * 320 * 2;
    ushort* WbF2 = (ushort*)p; p += (size_t)224 * 224 * 2;
    ushort* WbG1 = (ushort*)p; p += (size_t)224 * 608 * 2;
    ushort* WbG2 = (ushort*)p; p += (size_t)224 * 224 * 2;
    float*  bpF1 = (float*)p;  p += 224 * 4;
    float*  bpF2 = (float*)p;  p += 224 * 4;
    float*  bpG1 = (float*)p;  p += 224 * 4;
    float*  bpG2 = (float*)p;  p += 224 * 4;
    float*  hsum = (float*)p;  p += 400 * 4;

    dim3 blk256(256);

    hipLaunchKernelGGL(convert_inputs_kernel, dim3(2 * L / 8), blk256, 0, stream,
                       sen1, sen2, Senb, Xcat);
    hipLaunchKernelGGL(transpose_bf16_kernel, dim3(L / 64, 5, 2), blk256, 0, stream,
                       sen1, sen2, St1, St2);
    hipLaunchKernelGGL(convert_weights_kernel, dim3(4 * 224), blk256, 0, stream,
                       F_w1, F_b1, F_w2, F_b2, G_w1, G_b1, G_w2, G_b2,
                       WbF1, bpF1, WbF2, bpF2, WbG1, bpG1, WbG2, bpG2);

    // F MLP (both sentences batched: M = 16384)
    hipLaunchKernelGGL(mfma_linear_kernel, dim3(2 * L / 16), dim3(64), 0, stream,
                       Senb, WbF1, bpF1, 320, h16, (float*)nullptr);
    hipLaunchKernelGGL(mfma_linear_kernel, dim3(2 * L / 16), dim3(64), 0, stream,
                       h16, WbF2, bpF2, 224, FaFb, (float*)nullptr);

    // fused flash attend (both directions), writes beta/alpha into Xcat
    hipLaunchKernelGGL(attend_mfma_kernel, dim3(2 * L / 64), blk256, 0, stream,
                       FaFb, St1, St2, Xcat);

    // G MLP (both sides batched)
    hipLaunchKernelGGL(mfma_linear_kernel, dim3(2 * L / 16), dim3(64), 0, stream,
                       Xcat, WbG1, bpG1, 608, h16, (float*)nullptr);
    hipLaunchKernelGGL(mfma_linear_kernel, dim3(2 * L / 16), dim3(64), 0, stream,
                       h16, WbG2, bpG2, 224, (ushort*)nullptr, v);

    hipLaunchKernelGGL(colsum_kernel, dim3(400), blk256, 0, stream, v, hsum);
    hipLaunchKernelGGL(head_kernel, dim3(1), blk256, 0, stream,
                       hsum, H_w1, H_b1, H_w2, H_b2, out);
}